// Round 6
// baseline (237.350 us; speedup 1.0000x reference)
//
#include <hip/hip_runtime.h>

// QuantumRecurrentUnit, exact Heisenberg closed form.
//   rev_q = (p_q + x_q)/2pi ;  sa=sin, ca=cos of the angle
//   p_q' = cos(th_q)*prefixprod_{j<=q} ca_j - sin(th_q)*(q<5 ? sa_q*sa_{q+1} : sa_5)
//
// v7 = v6 geometry retuned to the measured stall model.
// v6 (S=64): 512 waves on 1024 SIMDs -- half the SIMDs idle, TOT=96, 86.9 us,
// ~2150 cy of wall per wave-step (vs ~140 cy issue): a large design-invariant
// per-step stall that extra waves only partially overlap (f(1)=1, f(2)~1.35,
// f(4.5)~2.6 from v1/v4/v6). Minimizing generations*TOT*f:
//   S=32 -> TOT=64, 65536 windows, 1024 one-wave blocks = EXACTLY 1 wave per
//   SIMD, single generation, zero idle SIMDs. Predicted ~64*2150 cy ~ 57 us.
// Everything else byte-identical to v6's verified structure:
//   - zero LDS / zero syncthreads; per-lane row loads (float4+float2, one
//     64-B line per row), group-of-8 double-buffered register prefetch with
//     sched_barrier(0) fences;
//   - clamp-to-row-0 burn-in + exact p=0 reset when a window crosses t=0
//     (only k=0; k=1's burn-in starts at t=0 with p=0, i.e. exact by itself);
//   - paired float4 stores: pair base row = 32k + even -> 48-B aligned;
//   - launch_bounds(64,2): 256-VGPR budget, no allocator crush.

constexpr int T = 1024;
constexpr int NQ = 6;
constexpr int S = 32;        // output steps per window
constexpr int W = 32;        // burn-in steps (accuracy knob -- unchanged)
constexpr int TOT = W + S;   // 64
constexpr int G = 8;         // rows per prefetch group
constexpr int NG = TOT / G;  // 8
constexpr int WPC = T / S;   // 32 windows per chain
constexpr float INV2PI = 0.15915494309189535f;  // v_sin/v_cos take revolutions

__global__ __launch_bounds__(64, 2) void qru_kernel(const float* __restrict__ x,
                                                    const float* __restrict__ w,
                                                    float* __restrict__ out) {
  const int lane = threadIdx.x;                  // 0..63
  const int gw = blockIdx.x * 64 + lane;         // global window id
  const int chain = gw / WPC;
  const int k = gw & (WPC - 1);                  // window index in chain
  const float* __restrict__ xb = x + (size_t)chain * (T * 16);
  float* __restrict__ ob = out + (size_t)chain * (T * NQ);
  const int tbase = k * S - W;                   // k=0: -32 (crosses t=0)

  float cth[NQ], sth[NQ];
#pragma unroll
  for (int q = 0; q < NQ; ++q) {
    const float th = w[q];
    cth[q] = cosf(th);
    sth[q] = sinf(th);
  }

  float p[NQ];
#pragma unroll
  for (int q = 0; q < NQ; ++q) p[q] = 0.0f;

  float bufA[G][NQ], bufB[G][NQ];  // prescaled angle row-groups
  float sv[NQ];                    // buffered even output row

  // Load rows [GI*G, GI*G+G) of this window into BUF, prescaled by 1/2pi.
#define LOADG(GI, BUF)                                                         \
  do {                                                                         \
    _Pragma("unroll") for (int r_ = 0; r_ < G; ++r_) {                         \
      int row_ = tbase + (GI) * G + r_;                                        \
      row_ = row_ < 0 ? 0 : row_; /* k=0 burn-in underrun: dummy row 0 */      \
      const float* rp_ = xb + (size_t)row_ * 16;                               \
      const float4 v4_ = *(const float4*)rp_;                                  \
      const float2 v2_ = *(const float2*)(rp_ + 4);                            \
      BUF[r_][0] = v4_.x * INV2PI;                                             \
      BUF[r_][1] = v4_.y * INV2PI;                                             \
      BUF[r_][2] = v4_.z * INV2PI;                                             \
      BUF[r_][3] = v4_.w * INV2PI;                                             \
      BUF[r_][4] = v2_.x * INV2PI;                                             \
      BUF[r_][5] = v2_.y * INV2PI;                                             \
    }                                                                          \
  } while (0)

  // Compute the G steps of group GI from BUF (all indices compile-time).
#define STEPS(GI, BUF)                                                         \
  do {                                                                         \
    _Pragma("unroll") for (int j_ = 0; j_ < G; ++j_) {                         \
      const int i_ = (GI) * G + j_;                                            \
      if (i_ == W) { /* window k=0 reaches t=0 exactly here: exact restart */  \
        const bool rs_ = (tbase + W == 0);                                     \
        _Pragma("unroll") for (int q_ = 0; q_ < NQ; ++q_)                      \
            p[q_] = rs_ ? 0.0f : p[q_];                                        \
      }                                                                        \
      float sa_[NQ], ca_[NQ];                                                  \
      _Pragma("unroll") for (int q_ = 0; q_ < NQ; ++q_) {                      \
        const float rev_ = fmaf(p[q_], INV2PI, BUF[j_][q_]);                   \
        sa_[q_] = __builtin_amdgcn_sinf(rev_);                                 \
        ca_[q_] = __builtin_amdgcn_cosf(rev_);                                 \
      }                                                                        \
      const float t01_ = ca_[0] * ca_[1];                                      \
      const float t23_ = ca_[2] * ca_[3];                                      \
      const float t45_ = ca_[4] * ca_[5];                                      \
      const float P2_ = t01_ * ca_[2];                                         \
      const float P3_ = t01_ * t23_;                                           \
      const float P4_ = P3_ * ca_[4];                                          \
      const float P5_ = P3_ * t45_;                                            \
      p[0] = cth[0] * ca_[0] - sth[0] * (sa_[0] * sa_[1]);                     \
      p[1] = cth[1] * t01_ - sth[1] * (sa_[1] * sa_[2]);                       \
      p[2] = cth[2] * P2_ - sth[2] * (sa_[2] * sa_[3]);                        \
      p[3] = cth[3] * P3_ - sth[3] * (sa_[3] * sa_[4]);                        \
      p[4] = cth[4] * P4_ - sth[4] * (sa_[4] * sa_[5]);                        \
      p[5] = cth[5] * P5_ - sth[5] * sa_[5];                                   \
      if (i_ >= W) { /* uniform: i_ is compile-time */                         \
        if (((i_ - W) & 1) == 0) { /* even output step: buffer the row */      \
          _Pragma("unroll") for (int q_ = 0; q_ < NQ; ++q_) sv[q_] = p[q_];    \
        } else { /* odd: emit rows i_-1,i_ as 3x float4 (48 B, 16B-aligned) */ \
          float* bp_ = ob + (size_t)(tbase + i_ - 1) * NQ;                     \
          *(float4*)(bp_ + 0) = make_float4(sv[0], sv[1], sv[2], sv[3]);       \
          *(float4*)(bp_ + 4) = make_float4(sv[4], sv[5], p[0], p[1]);         \
          *(float4*)(bp_ + 8) = make_float4(p[2], p[3], p[4], p[5]);           \
        }                                                                      \
      }                                                                        \
    }                                                                          \
  } while (0)

  LOADG(0, bufA);
#pragma unroll
  for (int gi = 0; gi < NG; gi += 2) {  // fully unrolled; gi compile-time
    if (gi + 1 < NG) LOADG(gi + 1, bufB);
    __builtin_amdgcn_sched_barrier(0);  // loads stay batched ahead of compute
    STEPS(gi, bufA);
    if (gi + 2 < NG) LOADG(gi + 2, bufA);
    __builtin_amdgcn_sched_barrier(0);
    STEPS(gi + 1, bufB);
  }
#undef LOADG
#undef STEPS
}

extern "C" void kernel_launch(void* const* d_in, const int* in_sizes, int n_in,
                              void* d_out, int out_size, void* d_ws, size_t ws_size,
                              hipStream_t stream) {
  const float* x = (const float*)d_in[0];
  const float* w = (const float*)d_in[1];
  float* out = (float*)d_out;
  const int chains = in_sizes[0] / (T * 16);        // 2048
  const int blocks = chains * WPC / 64;             // 1024 one-wave blocks
  qru_kernel<<<blocks, 64, 0, stream>>>(x, w, out);
}